// Round 9
// baseline (658.720 us; speedup 1.0000x reference)
//
#include <hip/hip_runtime.h>
#include <cstdint>
#include <type_traits>

#define MDIM 4096
#define NDIM 9216
#define KDIM 3072
#define KP   3136   // 3072 + 32 lora + 32 zero pad
#define NKT2 97     // GEMM covers 97 K-tiles of 32 (3104 cols)

#define QROWS 4
#define QB2 1024           // quant blocks (4 rows each)

typedef unsigned int u32;
typedef unsigned short u16;
typedef float f32x4 __attribute__((ext_vector_type(4)));
typedef __bf16 bf16x8 __attribute__((ext_vector_type(8)));

__device__ __forceinline__ u16 f2bf(float f) {
  u32 u = __float_as_uint(f);
  u32 r = u + 0x7fffu + ((u >> 16) & 1u);   // round-to-nearest-even
  return (u16)(r >> 16);
}

__device__ __forceinline__ float frcp(float f) { return __builtin_amdgcn_rcpf(f); }

__device__ __forceinline__ void gld_lds16(const void* g, void* l) {
  __builtin_amdgcn_global_load_lds((__attribute__((address_space(1))) void*)g,
                                   (__attribute__((address_space(3))) void*)l,
                                   16, 0, 0);
}

// ---------------- kernel 1: activation smooth+quant+lora_act, 4 rows/block (R4-exact) ----------------
__global__ __launch_bounds__(256) void k_quant(const float* __restrict__ x,
                        const float* __restrict__ lora_down, const float* __restrict__ smooth,
                        u16* __restrict__ Aex) {
  __shared__ float xs_s[QROWS][KDIM];   // 48 KB
  __shared__ float part[64 * 32];       // 8 KB  [chunk][rank]
  const int tid = threadIdx.x;
  const int m0 = blockIdx.x * QROWS;
  const int sub = tid & 15;

  #pragma unroll
  for (int r = 0; r < QROWS; ++r) {
    const float* xr = x + (size_t)(m0 + r) * KDIM;
    u16* arow = Aex + (size_t)(m0 + r) * KP;
    #pragma unroll
    for (int p = 0; p < 3; ++p) {
      int g = p * 16 + (tid >> 4);
      int k0 = g * 64 + sub * 4;
      float4 xv = *(const float4*)(xr + k0);
      float4 sv = *(const float4*)(smooth + k0);
      float a0 = xv.x * frcp(sv.x), a1 = xv.y * frcp(sv.y);
      float a2 = xv.z * frcp(sv.z), a3 = xv.w * frcp(sv.w);
      xs_s[r][k0+0] = a0; xs_s[r][k0+1] = a1; xs_s[r][k0+2] = a2; xs_s[r][k0+3] = a3;
      float am = fmaxf(fmaxf(fabsf(a0), fabsf(a1)), fmaxf(fabsf(a2), fabsf(a3)));
      am = fmaxf(am, __shfl_xor(am, 8, 16));
      am = fmaxf(am, __shfl_xor(am, 4, 16));
      am = fmaxf(am, __shfl_xor(am, 2, 16));
      am = fmaxf(am, __shfl_xor(am, 1, 16));
      float asc = fmaxf(am * (1.0f / 7.0f), 1e-8f);
      float iasc = frcp(asc);
      float q0 = fminf(7.f, fmaxf(-8.f, rintf(a0 * iasc)));
      float q1 = fminf(7.f, fmaxf(-8.f, rintf(a1 * iasc)));
      float q2 = fminf(7.f, fmaxf(-8.f, rintf(a2 * iasc)));
      float q3 = fminf(7.f, fmaxf(-8.f, rintf(a3 * iasc)));
      float d0 = q0 * asc, d1 = q1 * asc, d2 = q2 * asc, d3 = q3 * asc;
      u32 lo = (u32)f2bf(d0) | ((u32)f2bf(d1) << 16);
      u32 hi = (u32)f2bf(d2) | ((u32)f2bf(d3) << 16);
      *(uint2*)(arow + k0) = make_uint2(lo, hi);
    }
    if (tid < 32) arow[3104 + tid] = 0;   // zero pad tail (unused by gemm; harmless)
  }
  __syncthreads();

  const int c  = tid >> 2;
  const int r8 = (tid & 3) * 8;
  float a[QROWS][8] = {};
  const float* lp = lora_down + (size_t)c * 32 + r8;
  #pragma unroll 2
  for (int i = 0; i < 48; ++i) {
    float4 l0 = *(const float4*)(lp);
    float4 l1 = *(const float4*)(lp + 4);
    #pragma unroll
    for (int r = 0; r < QROWS; ++r) {
      float xv = xs_s[r][i * 64 + c];
      a[r][0] = fmaf(xv, l0.x, a[r][0]); a[r][1] = fmaf(xv, l0.y, a[r][1]);
      a[r][2] = fmaf(xv, l0.z, a[r][2]); a[r][3] = fmaf(xv, l0.w, a[r][3]);
      a[r][4] = fmaf(xv, l1.x, a[r][4]); a[r][5] = fmaf(xv, l1.y, a[r][5]);
      a[r][6] = fmaf(xv, l1.z, a[r][6]); a[r][7] = fmaf(xv, l1.w, a[r][7]);
    }
    lp += 64 * 32;
  }
  #pragma unroll 1
  for (int r = 0; r < QROWS; ++r) {
    __syncthreads();
    *(float4*)(&part[c * 32 + r8])     = make_float4(a[r][0], a[r][1], a[r][2], a[r][3]);
    *(float4*)(&part[c * 32 + r8 + 4]) = make_float4(a[r][4], a[r][5], a[r][6], a[r][7]);
    __syncthreads();
    if (tid < 32) {
      float s = 0.f;
      #pragma unroll 8
      for (int cc = 0; cc < 64; ++cc) s += part[cc * 32 + tid];
      Aex[(size_t)(m0 + r) * KP + 3072 + tid] = f2bf(s);   // LORA_SCALE = 1.0
    }
  }
}

// ---------------- kernel 2: 256x256 MFMA GEMM with FUSED int4 B-dequant ----------------
// R4 ring (4-slot, BK=32, stage distance 3, rolling frags) with B staged by in-kernel
// dequant: per iter, thread loads 2 u32 of qweight (+2 wscales) for K-tile kt+3, and
// dequantizes the PREVIOUS iter's q-data (K-tile kt+2) into slot (kt+2)&3 B-half via
// ds_write_b128 at the same swizzled offsets the ds_reads use. A-half stays gld_lds.
// vmcnt(2) mid-iter: retires q(kt+2) (issued iter kt-1, ~full iteration ago) and
// A-gld(kt-1); keeps this iter's 2 A-glds in flight. lgkmcnt(0) before each barrier
// publishes ds_writes cross-wave. Slot WAR: B write (kt+2) vs last read (rolls at
// iter kt-3) separated by 2 barriers; A write (kt+3) vs last read (MFMA kt-1) by 1. OK.
// K-tile 96 = lora_up columns: loaded as floats at peeled iter 93, written at 94.
// Layout probe (int8-raw vs int32-sign-extended) once; branch-free templated loop.
__global__ __launch_bounds__(512) void k_gemm(const u16* __restrict__ A, const u32* __restrict__ qw,
                                              const float* __restrict__ wsc, const float* __restrict__ lora_up,
                                              const float* __restrict__ bias, const float* __restrict__ norm_q,
                                              const float* __restrict__ norm_k, const float* __restrict__ rot,
                                              float* __restrict__ out) {
  extern __shared__ u16 lds[];   // 4 slots * 16384 u16 = 128 KB
  const int tid  = threadIdx.x;
  const int lane = tid & 63;
  const int wave = tid >> 6;
  const int m0 = blockIdx.y * 256;
  const int n0 = blockIdx.x * 256;
  const int wm = (wave >> 2) * 128;
  const int wn = (wave & 3) * 64;
  const int lr = lane & 15;
  const int lq = lane >> 4;

  // ---- staging geometry ----
  const u16 *pA0, *pA1;
  int la0, la1, lb0, lb1;
  int qoff0, qoff1, nr0, nr1, kc0, kc1;
  {
    auto geo = [&](int p, int& r, int& kc) {
      int pr = p >> 3, cs = p & 7;
      int c  = cs ^ (pr & 7);
      r  = pr * 2 + (c >> 2);    // logical row (row-paired layout)
      kc = c & 3;                // 8-col chunk within BK=32
    };
    int r, kc;
    int p0 = tid, p1 = 512 + tid;
    geo(p0, r, kc);
    pA0 = A + (size_t)(m0 + r) * KP + kc * 8;
    nr0 = n0 + r; kc0 = kc; qoff0 = nr0 * 384 + kc;
    la0 = p0 * 8; lb0 = 8192 + p0 * 8;
    geo(p1, r, kc);
    pA1 = A + (size_t)(m0 + r) * KP + kc * 8;
    nr1 = n0 + r; kc1 = kc; qoff1 = nr1 * 384 + kc;
    la1 = p1 * 8; lb1 = 8192 + p1 * 8;
  }

  // ---- fragment LDS offsets (u16 units within a slot) ----
  int aoff[8], boff[4];
  #pragma unroll
  for (int t = 0; t < 8; ++t) {
    int ra = wm + t * 16 + lr;
    int pr = ra >> 1, c = (ra & 1) * 4 + lq;
    aoff[t] = pr * 64 + ((c ^ (pr & 7)) * 8);
  }
  #pragma unroll
  for (int t = 0; t < 4; ++t) {
    int rb = wn + t * 16 + lr;
    int pr = rb >> 1, c = (rb & 1) * 4 + lq;
    boff[t] = 8192 + pr * 64 + ((c ^ (pr & 7)) * 8);
  }

  f32x4 acc[8][4] = {};

  // ---- layout probe: every wave checks the same 64 words -> uniform without LDS ----
  u32 probe = qw[lane];
  bool okp = (probe >> 8) == ((probe & 0x80u) ? 0xffffffu : 0u);
  const bool f1 = __all(okp);   // true: int8 stored as sign-extended int32

  auto run = [&](auto f1c) {
    constexpr bool F1 = decltype(f1c)::value;
    uint4 qa, qb; float wsa, wsb;

    auto loadq = [&](int ktg) {
      if constexpr (F1) {
        qa = ((const uint4*)qw)[qoff0 + ktg * 4];
        qb = ((const uint4*)qw)[qoff1 + ktg * 4];
      } else {
        qa.x = qw[qoff0 + ktg * 4];
        qb.x = qw[qoff1 + ktg * 4];
      }
      wsa = wsc[(ktg >> 1) * NDIM + nr0];
      wsb = wsc[(ktg >> 1) * NDIM + nr1];
    };
    auto deqw = [&](int slot) {
      u16* wsl = lds + (slot << 14);
      u32 w0, w1;
      if constexpr (F1) {
        w0 = (qa.x & 0xffu) | ((qa.y & 0xffu) << 8) | ((qa.z & 0xffu) << 16) | ((qa.w & 0xffu) << 24);
        w1 = (qb.x & 0xffu) | ((qb.y & 0xffu) << 8) | ((qb.z & 0xffu) << 16) | ((qb.w & 0xffu) << 24);
      } else { w0 = qa.x; w1 = qb.x; }
      u32 o0[4], o1[4];
      #pragma unroll
      for (int b = 0; b < 4; ++b) {
        int by = (int)((w0 >> (8 * b)) & 0xffu);
        int lo = (by << 28) >> 28, hi = (by << 24) >> 28;
        o0[b] = (u32)f2bf((float)lo * wsa) | ((u32)f2bf((float)hi * wsa) << 16);
        by = (int)((w1 >> (8 * b)) & 0xffu);
        lo = (by << 28) >> 28; hi = (by << 24) >> 28;
        o1[b] = (u32)f2bf((float)lo * wsb) | ((u32)f2bf((float)hi * wsb) << 16);
      }
      *(uint4*)(wsl + lb0) = make_uint4(o0[0], o0[1], o0[2], o0[3]);
      *(uint4*)(wsl + lb1) = make_uint4(o1[0], o1[1], o1[2], o1[3]);
    };

    // ---- prologue: A slots 0,1,2 via gld; B0,B1 dequant-written; q(2) carried ----
    #pragma unroll
    for (int s = 0; s < 3; ++s) {
      u16* sl = lds + (s << 14);
      gld_lds16(pA0, sl + la0); gld_lds16(pA1, sl + la1);
      pA0 += 32; pA1 += 32;
    }
    loadq(0);
    asm volatile("s_waitcnt vmcnt(0)" ::: "memory");
    deqw(0);
    loadq(1);
    asm volatile("s_waitcnt vmcnt(0)" ::: "memory");
    deqw(1);
    loadq(2);   // consumed at iter 0
    asm volatile("s_waitcnt lgkmcnt(0)" ::: "memory");
    __builtin_amdgcn_s_barrier();
    asm volatile("" ::: "memory");

    bf16x8 af[8], bf[4];
    #pragma unroll
    for (int t = 0; t < 8; ++t) af[t] = *(const bf16x8*)&lds[aoff[t]];
    #pragma unroll
    for (int t = 0; t < 4; ++t) bf[t] = *(const bf16x8*)&lds[boff[t]];

    // ---- main loop: K-tiles 0..92, fully branch-free ----
    #pragma unroll 1
    for (int kt = 0; kt < 93; ++kt) {
      u16* stl = lds + (((kt + 3) & 3) << 14);
      const u16* nsl = lds + (((kt + 1) & 3) << 14);
      gld_lds16(pA0, stl + la0); gld_lds16(pA1, stl + la1);
      pA0 += 32; pA1 += 32;
      asm volatile("s_waitcnt vmcnt(2)" ::: "memory");   // q(kt+2), A(kt-1) retired
      deqw((kt + 2) & 3);
      loadq(kt + 3);
      __builtin_amdgcn_s_setprio(1);
      #pragma unroll
      for (int t = 0; t < 8; ++t) {
        #pragma unroll
        for (int tj = 0; tj < 4; ++tj)
          acc[t][tj] = __builtin_amdgcn_mfma_f32_16x16x32_bf16(af[t], bf[tj], acc[t][tj], 0, 0, 0);
        af[t] = *(const bf16x8*)&nsl[aoff[t]];
      }
      #pragma unroll
      for (int t = 0; t < 4; ++t) bf[t] = *(const bf16x8*)&nsl[boff[t]];
      __builtin_amdgcn_s_setprio(0);
      // pins: 4 MFMA first, then B writes + q loads, then MFMA/DS interleave
      __builtin_amdgcn_sched_group_barrier(0x008, 4, 0);   // MFMA
      __builtin_amdgcn_sched_group_barrier(0x200, 2, 0);   // DS_WRITE
      __builtin_amdgcn_sched_group_barrier(0x020, 4, 0);   // VMEM_READ (q/ws)
      #pragma unroll
      for (int g = 0; g < 7; ++g) {
        __builtin_amdgcn_sched_group_barrier(0x008, 4, 0); // MFMA
        __builtin_amdgcn_sched_group_barrier(0x100, 1, 0); // DS_READ
      }
      __builtin_amdgcn_sched_group_barrier(0x100, 5, 0);   // trailing ds_reads
      asm volatile("s_waitcnt lgkmcnt(0)" ::: "memory");   // publish ds_writes
      __builtin_amdgcn_s_barrier();
      asm volatile("" ::: "memory");
    }

    // ---- peel kt=93: last A gld (K96), B95 write, lora load ----
    float4 fa0, fa1, fb0, fb1;
    {
      u16* stl = lds + (0 << 14);                    // slot (96&3)=0, A-half
      const u16* nsl = lds + ((94 & 3) << 14);       // slot 2
      gld_lds16(pA0, stl + la0); gld_lds16(pA1, stl + la1);
      asm volatile("s_waitcnt vmcnt(2)" ::: "memory");
      deqw(95 & 3);                                  // B95 -> slot 3
      const float4* lu4 = (const float4*)lora_up;
      fa0 = lu4[nr0 * 8 + kc0 * 2]; fa1 = lu4[nr0 * 8 + kc0 * 2 + 1];
      fb0 = lu4[nr1 * 8 + kc1 * 2]; fb1 = lu4[nr1 * 8 + kc1 * 2 + 1];
      __builtin_amdgcn_s_setprio(1);
      #pragma unroll
      for (int t = 0; t < 8; ++t) {
        #pragma unroll
        for (int tj = 0; tj < 4; ++tj)
          acc[t][tj] = __builtin_amdgcn_mfma_f32_16x16x32_bf16(af[t], bf[tj], acc[t][tj], 0, 0, 0);
        af[t] = *(const bf16x8*)&nsl[aoff[t]];
      }
      #pragma unroll
      for (int t = 0; t < 4; ++t) bf[t] = *(const bf16x8*)&nsl[boff[t]];
      __builtin_amdgcn_s_setprio(0);
      asm volatile("s_waitcnt lgkmcnt(0)" ::: "memory");
      __builtin_amdgcn_s_barrier();
      asm volatile("" ::: "memory");
    }
    // ---- peel kt=94: write B96 (lora), cluster K94 ----
    {
      asm volatile("s_waitcnt vmcnt(0)" ::: "memory");   // lora floats + A96 retired
      u16* w96 = lds + (0 << 14);
      u32 a0 = (u32)f2bf(fa0.x) | ((u32)f2bf(fa0.y) << 16);
      u32 a1 = (u32)f2bf(fa0.z) | ((u32)f2bf(fa0.w) << 16);
      u32 a2 = (u32)f2bf(fa1.x) | ((u32)f2bf(fa1.y) << 16);
      u32 a3 = (u32)f2bf(fa1.z) | ((u32)f2bf(fa1.w) << 16);
      *(uint4*)(w96 + lb0) = make_uint4(a0, a1, a2, a3);
      u32 b0 = (u32)f2bf(fb0.x) | ((u32)f2bf(fb0.y) << 16);
      u32 b1 = (u32)f2bf(fb0.z) | ((u32)f2bf(fb0.w) << 16);
      u32 b2 = (u32)f2bf(fb1.x) | ((u32)f2bf(fb1.y) << 16);
      u32 b3 = (u32)f2bf(fb1.z) | ((u32)f2bf(fb1.w) << 16);
      *(uint4*)(w96 + lb1) = make_uint4(b0, b1, b2, b3);
      const u16* nsl = lds + ((95 & 3) << 14);       // slot 3
      __builtin_amdgcn_s_setprio(1);
      #pragma unroll
      for (int t = 0; t < 8; ++t) {
        #pragma unroll
        for (int tj = 0; tj < 4; ++tj)
          acc[t][tj] = __builtin_amdgcn_mfma_f32_16x16x32_bf16(af[t], bf[tj], acc[t][tj], 0, 0, 0);
        af[t] = *(const bf16x8*)&nsl[aoff[t]];
      }
      #pragma unroll
      for (int t = 0; t < 4; ++t) bf[t] = *(const bf16x8*)&nsl[boff[t]];
      __builtin_amdgcn_s_setprio(0);
      asm volatile("s_waitcnt lgkmcnt(0)" ::: "memory");
      __builtin_amdgcn_s_barrier();
      asm volatile("" ::: "memory");
    }
    // ---- peel kt=95 (rolls load K96 frags from slot 0) + tail K96 ----
    {
      const u16* nsl = lds + (0 << 14);
      #pragma unroll
      for (int t = 0; t < 8; ++t) {
        #pragma unroll
        for (int tj = 0; tj < 4; ++tj)
          acc[t][tj] = __builtin_amdgcn_mfma_f32_16x16x32_bf16(af[t], bf[tj], acc[t][tj], 0, 0, 0);
        af[t] = *(const bf16x8*)&nsl[aoff[t]];
      }
      #pragma unroll
      for (int t = 0; t < 4; ++t) bf[t] = *(const bf16x8*)&nsl[boff[t]];
      #pragma unroll
      for (int t = 0; t < 8; ++t)
        #pragma unroll
        for (int tj = 0; tj < 4; ++tj)
          acc[t][tj] = __builtin_amdgcn_mfma_f32_16x16x32_bf16(af[t], bf[tj], acc[t][tj], 0, 0, 0);
    }
  };
  if (f1) run(std::integral_constant<bool, true>{});
  else    run(std::integral_constant<bool, false>{});

  // ---- epilogue (R4-exact).  C/D layout: col = lane&15, row = (lane>>4)*4 + reg ----
  const int sel = (blockIdx.x >= 24) ? 2 : (blockIdx.x >= 12 ? 1 : 0);

  float bv[4];
  #pragma unroll
  for (int tj = 0; tj < 4; ++tj) bv[tj] = bias[n0 + wn + tj * 16 + lr];
  #pragma unroll
  for (int ti = 0; ti < 8; ++ti)
    #pragma unroll
    for (int tj = 0; tj < 4; ++tj)
      #pragma unroll
      for (int rg = 0; rg < 4; ++rg)
        acc[ti][tj][rg] += bv[tj];

  if (sel == 2) {
    #pragma unroll
    for (int tj = 0; tj < 4; ++tj) {
      int n = n0 + wn + tj * 16 + lr;
      #pragma unroll
      for (int ti = 0; ti < 8; ++ti) {
        int mr = m0 + wm + ti * 16 + lq * 4;
        #pragma unroll
        for (int rg = 0; rg < 4; ++rg)
          out[(size_t)(mr + rg) * NDIM + n] = acc[ti][tj][rg];
      }
    }
    return;
  }

  __syncthreads();   // all waves done with LDS ring -> safe to reuse
  float* ssq = (float*)lds;
  #pragma unroll
  for (int ti = 0; ti < 8; ++ti) {
    float pr4[4];
    #pragma unroll
    for (int rg = 0; rg < 4; ++rg) {
      float s = 0.f;
      #pragma unroll
      for (int tj = 0; tj < 4; ++tj) s += acc[ti][tj][rg] * acc[ti][tj][rg];
      pr4[rg] = s;
    }
    #pragma unroll
    for (int off = 1; off < 16; off <<= 1)
      #pragma unroll
      for (int rg = 0; rg < 4; ++rg) pr4[rg] += __shfl_xor(pr4[rg], off);
    #pragma unroll
    for (int rg = 0; rg < 4; ++rg)
      if (lr == (ti & 3) * 4 + rg)
        ssq[(wn >> 6) * 256 + wm + ti * 16 + lq * 4 + rg] = pr4[rg];
  }
  __syncthreads();

  const float* nrm = sel ? norm_k : norm_q;
  float gm[4];
  #pragma unroll
  for (int tj = 0; tj < 4; ++tj) gm[tj] = nrm[(wn & 64) + tj * 16 + lr];
  const float2* rot2 = (const float2*)rot;
  const float sgn = (lr & 1) ? 1.0f : -1.0f;
  const int hb = (wn >> 7) * 512;

  #pragma unroll
  for (int ti = 0; ti < 8; ++ti) {
    #pragma unroll
    for (int rg = 0; rg < 4; ++rg) {
      int row = wm + ti * 16 + lq * 4 + rg;
      float tot = ssq[hb + row] + ssq[hb + 256 + row];
      float rs = rsqrtf(tot * (1.0f / 128.0f) + 1e-6f);
      int m = m0 + row;
      #pragma unroll
      for (int tj = 0; tj < 4; ++tj) {
        int nl = (wn & 64) + tj * 16 + lr;          // head-local col
        float v = acc[ti][tj][rg] * rs * gm[tj];
        float p = __shfl_xor(v, 1);                 // rope partner (same row, col^1)
        float2 cs = rot2[(size_t)m * 64 + (nl >> 1)];
        out[(size_t)m * NDIM + n0 + wn + tj * 16 + lr] = v * cs.x + sgn * (p * cs.y);
      }
    }
  }
}

extern "C" void kernel_launch(void* const* d_in, const int* in_sizes, int n_in,
                              void* d_out, int out_size, void* d_ws, size_t ws_size,
                              hipStream_t stream) {
  const float* x         = (const float*)d_in[0];
  const u32*   qweight   = (const u32*)d_in[1];
  const float* wscales   = (const float*)d_in[2];
  const float* bias      = (const float*)d_in[3];
  const float* lora_down = (const float*)d_in[4];
  const float* lora_up   = (const float*)d_in[5];
  const float* smooth    = (const float*)d_in[6];
  const float* norm_q    = (const float*)d_in[7];
  const float* norm_k    = (const float*)d_in[8];
  const float* rot       = (const float*)d_in[9];
  float* out = (float*)d_out;

  u16* Aex = (u16*)d_ws;                               // 4096*3136 bf16 (only workspace now)

  static bool attr_set = false;
  if (!attr_set) {
    hipFuncSetAttribute(reinterpret_cast<const void*>(k_gemm),
                        hipFuncAttributeMaxDynamicSharedMemorySize, 131072);
    attr_set = true;
  }

  k_quant<<<QB2, 256, 0, stream>>>(x, lora_down, smooth, Aex);
  k_gemm<<<dim3(NDIM / 256, MDIM / 256), 512, 131072, stream>>>(Aex, qweight, wscales, lora_up,
                                                                bias, norm_q, norm_k, rot, out);
}